// Round 5
// baseline (238.276 us; speedup 1.0000x reference)
//
#include <hip/hip_runtime.h>
#include <hip/hip_bf16.h>
#include <stdint.h>

typedef unsigned short u16;
typedef __attribute__((ext_vector_type(8))) short short8;
typedef __attribute__((ext_vector_type(4))) float f32x4;

#define BATCH 4096
#define DIN   1024
#define NH    1024
#define KTOT  2048

__device__ __forceinline__ void gload_lds16(const void* gp, void* lp) {
    __builtin_amdgcn_global_load_lds(
        (const __attribute__((address_space(1))) uint32_t*)gp,
        (__attribute__((address_space(3))) uint32_t*)lp, 16, 0, 0);
}

__device__ __forceinline__ u16 f2bf(float f) {   // round-to-nearest-even
    uint32_t t; __builtin_memcpy(&t, &f, 4);
    uint32_t r = (t + 0x7FFFu + ((t >> 16) & 1u)) >> 16;
    return (u16)r;
}
__device__ __forceinline__ float hsig(float z) {
    return fminf(fmaxf(fmaf(z, 0.2f, 0.5f), 0.0f), 1.0f);
}
__device__ __forceinline__ float fast_tanh(float x) {
    x = fminf(fmaxf(x, -12.0f), 12.0f);
    float e = __expf(2.0f * x);
    return (e - 1.0f) / (e + 1.0f);
}

// ---------------------------------------------------------------------------
// Prep kernel.
//   blocks [0, 2048):      weights cast+transpose+concat -> Bt[(g*NH+n)][KTOT]
//   blocks [2048, 18432):  activations cast+concat -> Apack in MFMA-FRAGMENT
//     layout: Apack[mtile][k2][lane][8] where m = mtile*16 + (lane&15),
//     k = k2*32 + (lane>>4)*8 + j.  A wave's A-frag read = contiguous 1 KB.
// ---------------------------------------------------------------------------
#define WT_BLOCKS 2048
__global__ __launch_bounds__(256) void prep_kernel(
    const float* __restrict__ x, const float* __restrict__ h0,
    const float* __restrict__ Wf, const float* __restrict__ Wi,
    const float* __restrict__ Wo, const float* __restrict__ Wc,
    const float* __restrict__ Uf, const float* __restrict__ Ui,
    const float* __restrict__ Uo, const float* __restrict__ Uc,
    u16* __restrict__ Bt, u16* __restrict__ Apack)
{
    __shared__ u16 tile[64][65];
    const int bid = blockIdx.x;
    const int tid = threadIdx.x;

    if (bid < WT_BLOCKS) {
        const int mz = bid >> 8;
        const float* srcs[8] = {Wf, Wi, Wo, Wc, Uf, Ui, Uo, Uc};
        const float* src = srcs[mz];
        const int g    = mz & 3;
        const int koff = (mz >> 2) << 10;
        const int k0 = ((bid >> 4) & 15) * 64;
        const int n0 = (bid & 15) * 64;

#pragma unroll
        for (int i = 0; i < 4; i++) {
            int idx = i * 256 + tid;
            int kk = idx >> 4, c = idx & 15;
            float4 v = *(const float4*)(src + (size_t)(k0 + kk) * NH + n0 + c * 4);
            u16* dst = &tile[kk][c * 4];
            dst[0] = f2bf(v.x); dst[1] = f2bf(v.y);
            dst[2] = f2bf(v.z); dst[3] = f2bf(v.w);
        }
        __syncthreads();
#pragma unroll
        for (int i = 0; i < 2; i++) {
            int idx = i * 256 + tid;
            int nn = idx >> 3, c = idx & 7;
            union { u16 v[8]; uint4 q; } pk;
#pragma unroll
            for (int j = 0; j < 8; j++) pk.v[j] = tile[c * 8 + j][nn];
            *(uint4*)(Bt + ((size_t)(g * NH + n0 + nn)) * KTOT + koff + k0 + c * 8) = pk.q;
        }
    } else {
        const int c  = (bid - WT_BLOCKS) * 256 + tid;
        const int m  = c >> 8;
        const int kc = (c & 255) * 8;
        const float* src = (kc < DIN) ? (x + (size_t)m * DIN + kc)
                                      : (h0 + (size_t)m * DIN + (kc - DIN));
        float4 v0 = *(const float4*)(src);
        float4 v1 = *(const float4*)(src + 4);
        union { u16 v[8]; uint4 q; } pk;
        pk.v[0] = f2bf(v0.x); pk.v[1] = f2bf(v0.y);
        pk.v[2] = f2bf(v0.z); pk.v[3] = f2bf(v0.w);
        pk.v[4] = f2bf(v1.x); pk.v[5] = f2bf(v1.y);
        pk.v[6] = f2bf(v1.z); pk.v[7] = f2bf(v1.w);
        // fragment-packed store
        const int mtile = m >> 4, amr = m & 15;
        const int k2 = kc >> 5, qd = (kc >> 3) & 3;
        const size_t dst = (((size_t)mtile * 64 + k2) * 64 + qd * 16 + amr) * 8;
        *(uint4*)(Apack + dst) = pk.q;
    }
}

// ---------------------------------------------------------------------------
// R15 GEMM: A direct-from-global (fragment-packed), B LDS-staged.
// R10-R14 all measured 78.5-80 us across 5 different schedules: the
// invariant was ~256 KB/tile/CU of LDS-pipe traffic (saturated DS pipe).
// This version removes the A side from LDS entirely:
//   - A frag loads: 8 x global_load_dwordx4 per ks-step per wave, each a
//     contiguous 1 KB burst (SGPR-ish base + lane*16), L1/L3-served,
//     register double-buffered (aE/aO) one ks-step ahead.
//   - B: LDS ring-3 (3 x 32 KB = 96 KB), staged with gload_lds (4
//     issues/wave/tile), chunk-XOR swizzle, read 8 x ds_read_b128/wave/tile.
// LDS traffic/tile/CU: 96 KB (was 256 KB) << MFMA wall.
// One s_barrier per K-tile.  Staging guard chain (no explicit vmcnt in
// loop): stageB(u+2) is issued immediately BEFORE the aE(u+1) register
// loads; the compiler's counted-vmcnt wait for aE(u+1) (at tile u+1 ks0
// MFMA, before the end-of-(u+1) barrier) therefore drains stageB(u+2) in
// every wave before any wave reads B(u+2) at tile u+2.  Ring-3 write
// hazard: slot (u+2)%3 was last read at tile u-1, before the end-of-(u-1)
// barrier, before this issue.  vmcnt never force-drained to 0 in-loop.
// ---------------------------------------------------------------------------
#define BM   256
#define BNG  64
#define BK   64
#define NT   (KTOT / BK)        // 32
#define BSLOT 16384             // u16 per B tile (256 rows x 64 k)

__global__ __launch_bounds__(512, 2) void lstm_gemm_kernel(
    const u16* __restrict__ Apack, const float* __restrict__ c0,
    const u16* __restrict__ Bt,
    const float* __restrict__ bfv, const float* __restrict__ biv,
    const float* __restrict__ bov, const float* __restrict__ bcv,
    float* __restrict__ out)
{
    extern __shared__ u16 smem[];            // 96 KiB dynamic LDS (B ring-3)

    const int tid  = threadIdx.x;
    const int wv   = tid >> 6;
    const int lane = tid & 63;
    const int wm = wv >> 2;                  // 0..1  m-half
    const int wn = wv & 3;                   // 0..3  16-col slice per gate

    // XCD-contiguous swizzle (bijective, grid 16x16 = 256 = 8 XCD x 32)
    const int lin = blockIdx.y * 16 + blockIdx.x;
    const int xcd = lin & 7, j = lin >> 3;
    const int nb  = xcd * 2 + (j & 1);
    const int mb  = j >> 1;
    const int m0  = mb * BM;
    const int n0  = nb * BNG;

    // ---- B staging constants ----
    const int l8   = lane >> 3;
    const int sc   = ((lane & 7) ^ l8) * 8;            // pre-swizzled chunk
    const int rowL = wv * 8 + l8;                      // 0..63 (n within gate)
    const u16* gB = Bt + (size_t)(n0 + rowL) * KTOT + sc;
    const int ldsOff = wv * 512;

    auto stageB = [&](int tt) {              // 4 gload issues / wave
        u16* ld = smem + (tt % 3) * BSLOT + ldsOff;
        const u16* g = gB + (size_t)tt * BK;
#pragma unroll
        for (int h = 0; h < 2; h++) {
            gload_lds16(g + (size_t)(2 * h) * NH * KTOT,     ld + h * 8192);
            gload_lds16(g + (size_t)(2 * h + 1) * NH * KTOT, ld + h * 8192 + 4096);
        }
    };

    // ---- fragment constants ----
    const int am   = lane & 15;
    const int quad = lane >> 4;
    const int a7   = am & 7;
    const int ck0 = ((quad) ^ a7) * 8;        // B un-swizzled chunk, ks=0
    const int ck1 = ((4 + quad) ^ a7) * 8;    // ks=1
    int rB[4];
#pragma unroll
    for (int g = 0; g < 4; g++) rB[g] = (g * 64 + wn * 16 + am) * BK;

    // A fragment-packed base: elem((mtile)*64 + k2)*512 + lane*8
    const u16* apl = Apack + ((size_t)(m0 >> 4) + wm * 8) * 32768 + lane * 8;

    f32x4 acc[8][4];
#pragma unroll
    for (int mt = 0; mt < 8; mt++)
#pragma unroll
        for (int g = 0; g < 4; g++)
            acc[mt][g] = (f32x4){0.f, 0.f, 0.f, 0.f};

    short8 aE[8], aO[8], b0_[4], b1_[4];

    // ---- prologue: B(0), B(1) staged; A(0, k2=0) in regs ----
    stageB(0);
    stageB(1);
#pragma unroll
    for (int mt = 0; mt < 8; mt++)
        aE[mt] = *(const short8*)(apl + (size_t)mt * 32768);
    asm volatile("s_waitcnt vmcnt(0)");
    __builtin_amdgcn_s_barrier();

    for (int u = 0; u < NT; ++u) {
        const u16* bs = smem + (u % 3) * BSLOT;

        // ---- ks0: MFMA(aE = A(u,ks0)); prefetch aO = A(u,ks1) ----
        {
            const size_t k2o = (size_t)(2 * u + 1) * 512;
#pragma unroll
            for (int mt = 0; mt < 8; mt++)
                aO[mt] = *(const short8*)(apl + (size_t)mt * 32768 + k2o);
#pragma unroll
            for (int g = 0; g < 4; g++)
                b0_[g] = *(const short8*)(bs + rB[g] + ck0);
            __builtin_amdgcn_s_setprio(1);
#pragma unroll
            for (int g = 0; g < 4; g++)
#pragma unroll
                for (int mt = 0; mt < 8; mt++)
                    acc[mt][g] = __builtin_amdgcn_mfma_f32_16x16x32_bf16(
                        aE[mt], b0_[g], acc[mt][g], 0, 0, 0);
            __builtin_amdgcn_s_setprio(0);
        }

        // ---- ks1: stage B(u+2); prefetch aE = A(u+1,ks0); MFMA(aO) ----
        {
            if (u + 2 < NT) stageB(u + 2);   // BEFORE aE loads (guard chain)
            if (u + 1 < NT) {
                const size_t k2n = (size_t)(2 * u + 2) * 512;
#pragma unroll
                for (int mt = 0; mt < 8; mt++)
                    aE[mt] = *(const short8*)(apl + (size_t)mt * 32768 + k2n);
            }
#pragma unroll
            for (int g = 0; g < 4; g++)
                b1_[g] = *(const short8*)(bs + rB[g] + ck1);
            __builtin_amdgcn_s_setprio(1);
#pragma unroll
            for (int g = 0; g < 4; g++)
#pragma unroll
                for (int mt = 0; mt < 8; mt++)
                    acc[mt][g] = __builtin_amdgcn_mfma_f32_16x16x32_bf16(
                        aO[mt], b1_[g], acc[mt][g], 0, 0, 0);
            __builtin_amdgcn_s_setprio(0);
            __builtin_amdgcn_s_barrier();
        }
    }

    // ---- epilogue: C/D layout col=lane&15, row=quad*4+reg ----
    const int col = n0 + wn * 16 + am;
    const float bb0 = bfv[col], bb1 = biv[col], bb2 = bov[col], bb3 = bcv[col];
    const size_t HN = (size_t)BATCH * NH;

#pragma unroll
    for (int mt = 0; mt < 8; mt++) {
#pragma unroll
        for (int r = 0; r < 4; r++) {
            const int row = m0 + wm * 128 + mt * 16 + quad * 4 + r;
            const size_t off = (size_t)row * NH + col;
            float zf = acc[mt][0][r] + bb0;
            float zi = acc[mt][1][r] + bb1;
            float zo = acc[mt][2][r] + bb2;
            float zc = acc[mt][3][r] + bb3;
            float fg = hsig(zf), ig = hsig(zi), og = hsig(zo);
            float ct = fast_tanh(zc);
            float cn = fg * c0[off] + ig * ct;
            float hn = og * fast_tanh(cn);
            out[off]          = hn;   // h
            out[HN + off]     = cn;   // c
            out[2 * HN + off] = hn;   // h (duplicate output)
        }
    }
}

extern "C" void kernel_launch(void* const* d_in, const int* in_sizes, int n_in,
                              void* d_out, int out_size, void* d_ws, size_t ws_size,
                              hipStream_t stream) {
    const float* x  = (const float*)d_in[0];
    const float* c0 = (const float*)d_in[1];
    const float* h0 = (const float*)d_in[2];
    const float* Wf = (const float*)d_in[3];
    const float* Wi = (const float*)d_in[4];
    const float* Wo = (const float*)d_in[5];
    const float* Wc = (const float*)d_in[6];
    const float* Uf = (const float*)d_in[7];
    const float* Ui = (const float*)d_in[8];
    const float* Uo = (const float*)d_in[9];
    const float* Uc = (const float*)d_in[10];
    const float* bf = (const float*)d_in[11];
    const float* bi = (const float*)d_in[12];
    const float* bo = (const float*)d_in[13];
    const float* bc = (const float*)d_in[14];

    u16* Bt    = (u16*)d_ws;                          // 4 x 1024 x 2048 bf16 = 16 MB
    u16* Apack = (u16*)d_ws + (size_t)4 * NH * KTOT;  // 4096 x 2048 bf16 = 16 MB

    static bool attr_done = false;
    if (!attr_done) {
        (void)hipFuncSetAttribute((const void*)lstm_gemm_kernel,
                                  hipFuncAttributeMaxDynamicSharedMemorySize,
                                  98304);
        attr_done = true;
    }

    prep_kernel<<<WT_BLOCKS + (BATCH * KTOT / 8) / 256, 256, 0, stream>>>(
        x, h0, Wf, Wi, Wo, Wc, Uf, Ui, Uo, Uc, Bt, Apack);

    dim3 gg(BATCH / BM, NH / BNG);   // 16 x 16 = 256 blocks, 1/CU, 8 waves/CU
    lstm_gemm_kernel<<<gg, 512, 98304, stream>>>(Apack, c0, Bt, bf, bi, bo, bc,
                                                 (float*)d_out);
}

// Round 7
// 212.769 us; speedup vs baseline: 1.1199x; 1.1199x over previous
//
#include <hip/hip_runtime.h>
#include <hip/hip_bf16.h>
#include <stdint.h>

typedef unsigned short u16;
typedef __attribute__((ext_vector_type(8))) short short8;
typedef __attribute__((ext_vector_type(4))) float f32x4;

#define BATCH 4096
#define DIN   1024
#define NH    1024
#define KTOT  2048

__device__ __forceinline__ void gload_lds16(const void* gp, void* lp) {
    __builtin_amdgcn_global_load_lds(
        (const __attribute__((address_space(1))) uint32_t*)gp,
        (__attribute__((address_space(3))) uint32_t*)lp, 16, 0, 0);
}

__device__ __forceinline__ u16 f2bf(float f) {   // round-to-nearest-even
    uint32_t t; __builtin_memcpy(&t, &f, 4);
    uint32_t r = (t + 0x7FFFu + ((t >> 16) & 1u)) >> 16;
    return (u16)r;
}
__device__ __forceinline__ float hsig(float z) {
    return fminf(fmaxf(fmaf(z, 0.2f, 0.5f), 0.0f), 1.0f);
}
__device__ __forceinline__ float fast_tanh(float x) {
    x = fminf(fmaxf(x, -12.0f), 12.0f);
    float e = __expf(2.0f * x);
    return (e - 1.0f) / (e + 1.0f);
}

// ---------------------------------------------------------------------------
// Fused prep kernel (proven R10-R14 version, unchanged):
//   blocks [0, 2048):      weight cast+transpose+concat -> Bt[(g*NH+n)][KTOT]
//   blocks [2048, 18432):  activation cast+concat       -> Abuf[m][KTOT]
// ---------------------------------------------------------------------------
#define WT_BLOCKS 2048
__global__ __launch_bounds__(256) void prep_kernel(
    const float* __restrict__ x, const float* __restrict__ h0,
    const float* __restrict__ Wf, const float* __restrict__ Wi,
    const float* __restrict__ Wo, const float* __restrict__ Wc,
    const float* __restrict__ Uf, const float* __restrict__ Ui,
    const float* __restrict__ Uo, const float* __restrict__ Uc,
    u16* __restrict__ Bt, u16* __restrict__ Abuf)
{
    __shared__ u16 tile[64][65];
    const int bid = blockIdx.x;
    const int tid = threadIdx.x;

    if (bid < WT_BLOCKS) {
        const int mz = bid >> 8;
        const float* srcs[8] = {Wf, Wi, Wo, Wc, Uf, Ui, Uo, Uc};
        const float* src = srcs[mz];
        const int g    = mz & 3;
        const int koff = (mz >> 2) << 10;
        const int k0 = ((bid >> 4) & 15) * 64;
        const int n0 = (bid & 15) * 64;

#pragma unroll
        for (int i = 0; i < 4; i++) {
            int idx = i * 256 + tid;
            int kk = idx >> 4, c = idx & 15;
            float4 v = *(const float4*)(src + (size_t)(k0 + kk) * NH + n0 + c * 4);
            u16* dst = &tile[kk][c * 4];
            dst[0] = f2bf(v.x); dst[1] = f2bf(v.y);
            dst[2] = f2bf(v.z); dst[3] = f2bf(v.w);
        }
        __syncthreads();
#pragma unroll
        for (int i = 0; i < 2; i++) {
            int idx = i * 256 + tid;
            int nn = idx >> 3, c = idx & 7;
            union { u16 v[8]; uint4 q; } pk;
#pragma unroll
            for (int j = 0; j < 8; j++) pk.v[j] = tile[c * 8 + j][nn];
            *(uint4*)(Bt + ((size_t)(g * NH + n0 + nn)) * KTOT + koff + k0 + c * 8) = pk.q;
        }
    } else {
        const int c  = (bid - WT_BLOCKS) * 256 + tid;
        const int m  = c >> 8;
        const int kc = (c & 255) * 8;
        const float* src = (kc < DIN) ? (x + (size_t)m * DIN + kc)
                                      : (h0 + (size_t)m * DIN + (kc - DIN));
        float4 v0 = *(const float4*)(src);
        float4 v1 = *(const float4*)(src + 4);
        union { u16 v[8]; uint4 q; } pk;
        pk.v[0] = f2bf(v0.x); pk.v[1] = f2bf(v0.y);
        pk.v[2] = f2bf(v0.z); pk.v[3] = f2bf(v0.w);
        pk.v[4] = f2bf(v1.x); pk.v[5] = f2bf(v1.y);
        pk.v[6] = f2bf(v1.z); pk.v[7] = f2bf(v1.w);
        *(uint4*)(Abuf + (size_t)m * KTOT + kc) = pk.q;
    }
}

// ---------------------------------------------------------------------------
// R17 GEMM = R12 K-loop (proven 79 us) + full-line epilogue.
// K-loop: 256m x (64n x 4g), BK=32, ring-4 LDS, 8 waves (2m x 4n), acc[8][4],
// register double-buffered frags, counted vmcnt(4), raw s_barrier.
// Epilogue (NEW): old version stored h/c/h in 64-B wave segments -> measured
// +34 MB FETCH (RFO write-allocate).  Now per 128-row half: z=acc+bias
// staged to LDS (4 x 128 x 64 f32 = 128 KB, reuses K-loop LDS, quad-XOR col
// swizzle, <=2-way both sides), then 16 thr/row store f32x4 -> 256-B
// contiguous full-line h/c/h stores + c0 reads.
// ---------------------------------------------------------------------------
#define BM   256
#define BNG  64
#define BK   32
#define NT   (KTOT / BK)        // 64
#define TILE_ELEMS (BM * BK)    // 8192 u16 = 16 KB
#define HN_ELEMS ((size_t)BATCH * NH)

__global__ __launch_bounds__(512, 2) void lstm_gemm_kernel(
    const u16* __restrict__ Abuf, const float* __restrict__ c0,
    const u16* __restrict__ Bt,
    const float* __restrict__ bfv, const float* __restrict__ biv,
    const float* __restrict__ bov, const float* __restrict__ bcv,
    float* __restrict__ out)
{
    extern __shared__ u16 smem[];            // 128 KiB dynamic LDS
    u16* As = smem;                          // [4][256][32]
    u16* Bs = smem + 4 * TILE_ELEMS;

    const int tid  = threadIdx.x;
    const int wv   = tid >> 6;
    const int lane = tid & 63;
    const int wm = wv >> 2;
    const int wn = wv & 3;
    const int m0 = blockIdx.x * BM;
    const int n0 = blockIdx.y * BNG;

    const int si = wv * 2;
    const int sr = lane >> 2;
    const int kc = (((lane & 3) ^ ((lane >> 3) & 3)) << 3);
    const int rA0 = si * 16 + sr, rA1 = rA0 + 16;
    const u16* aS0 = Abuf + (size_t)(m0 + rA0) * KTOT + kc;
    const u16* aS1 = Abuf + (size_t)(m0 + rA1) * KTOT + kc;
    const u16* bS0 = Bt + (size_t)((rA0 >> 6) * NH + n0 + (rA0 & 63)) * KTOT + kc;
    const u16* bS1 = Bt + (size_t)((rA1 >> 6) * NH + n0 + (rA1 & 63)) * KTOT + kc;
    const int ldsA0 = si * 512, ldsA1 = ldsA0 + 512;

    const int am   = lane & 15;
    const int quad = lane >> 4;
    const int pchunk = ((quad ^ ((am >> 1) & 3)) << 3);
    int aOff[8], bOff[4];
#pragma unroll
    for (int mt = 0; mt < 8; mt++)
        aOff[mt] = (wm * 128 + mt * 16 + am) * BK + pchunk;
#pragma unroll
    for (int g = 0; g < 4; g++)
        bOff[g] = (g * 64 + wn * 16 + am) * BK + pchunk;

    f32x4 acc[8][4];
#pragma unroll
    for (int mt = 0; mt < 8; mt++)
#pragma unroll
        for (int g = 0; g < 4; g++)
            acc[mt][g] = (f32x4){0.f, 0.f, 0.f, 0.f};

    auto stage = [&](int S) {
        const int slot = S & 3;
        const size_t ko = (size_t)S * BK;
        u16* ad = As + slot * TILE_ELEMS;
        u16* bd = Bs + slot * TILE_ELEMS;
        gload_lds16(aS0 + ko, ad + ldsA0);
        gload_lds16(aS1 + ko, ad + ldsA1);
        gload_lds16(bS0 + ko, bd + ldsA0);
        gload_lds16(bS1 + ko, bd + ldsA1);
    };
    auto loadFrags = [&](int t, short8 (&fa)[8], short8 (&fb)[4]) {
        const u16* as = As + (t & 3) * TILE_ELEMS;
        const u16* bs = Bs + (t & 3) * TILE_ELEMS;
#pragma unroll
        for (int mt = 0; mt < 8; mt++)
            fa[mt] = *(const short8*)(as + aOff[mt]);
#pragma unroll
        for (int g = 0; g < 4; g++)
            fb[g] = *(const short8*)(bs + bOff[g]);
    };
    auto mfmaStep = [&](short8 (&fa)[8], short8 (&fb)[4]) {
        __builtin_amdgcn_s_setprio(1);
#pragma unroll
        for (int g = 0; g < 4; g++)
#pragma unroll
            for (int mt = 0; mt < 8; mt++)
                acc[mt][g] = __builtin_amdgcn_mfma_f32_16x16x32_bf16(
                    fa[mt], fb[g], acc[mt][g], 0, 0, 0);
        __builtin_amdgcn_s_setprio(0);
    };

    short8 fA0[8], fB0[4], fA1[8], fB1[4];

    stage(0);
    stage(1);
    stage(2);
    asm volatile("s_waitcnt vmcnt(4)");
    __builtin_amdgcn_s_barrier();
    loadFrags(0, fA0, fB0);

    for (int T = 0; T < NT; T += 2) {
        loadFrags(T + 1, fA1, fB1);
        if (T + 3 < NT) stage(T + 3);
        mfmaStep(fA0, fB0);
        asm volatile("s_waitcnt vmcnt(4)");
        __builtin_amdgcn_s_barrier();

        if (T + 2 < NT) loadFrags(T + 2, fA0, fB0);
        if (T + 4 < NT) stage(T + 4);
        mfmaStep(fA1, fB1);
        asm volatile("s_waitcnt vmcnt(4)");
        __builtin_amdgcn_s_barrier();
    }

    // ================= full-line epilogue =================
    const int colE = n0 + wn * 16 + am;
    const float bb0 = bfv[colE], bb1 = biv[colE], bb2 = bov[colE], bb3 = bcv[colE];
    float* zb = (float*)smem;                // [4][128][64] f32 = 128 KB

#pragma unroll 1
    for (int h = 0; h < 2; h++) {
        __syncthreads();                     // LDS reuse / half-swap guard
        if (wm == h) {
            const int pc = (wn * 16 + am) ^ (quad << 4);   // quad-XOR swizzle
#pragma unroll
            for (int mt = 0; mt < 8; mt++) {
#pragma unroll
                for (int r = 0; r < 4; r++) {
                    const int row = mt * 16 + quad * 4 + r;   // 0..127
                    float* zr = zb + (size_t)row * 64 + pc;
                    zr[0 * 8192] = acc[mt][0][r] + bb0;
                    zr[1 * 8192] = acc[mt][1][r] + bb1;
                    zr[2 * 8192] = acc[mt][2][r] + bb2;
                    zr[3 * 8192] = acc[mt][3][r] + bb3;
                }
            }
        }
        __syncthreads();
#pragma unroll 1
        for (int p = 0; p < 4; p++) {
            const int row = p * 32 + (tid >> 4);              // 0..127
            const int cs  = (tid & 15) * 4;
            const int pcs = cs ^ (((row >> 2) & 3) << 4);     // un-swizzle
            const float* zr = zb + (size_t)row * 64;
            f32x4 vf = *(const f32x4*)(zr + 0 * 8192 + pcs);
            f32x4 vi = *(const f32x4*)(zr + 1 * 8192 + pcs);
            f32x4 vo = *(const f32x4*)(zr + 2 * 8192 + pcs);
            f32x4 vc = *(const f32x4*)(zr + 3 * 8192 + pcs);
            const int grow = m0 + h * 128 + row;
            const size_t off = (size_t)grow * NH + n0 + cs;
            f32x4 c0v = *(const f32x4*)(c0 + off);
            f32x4 hnv, cnv;
#pragma unroll
            for (int j = 0; j < 4; j++) {
                float fg = hsig(vf[j]), ig = hsig(vi[j]), og = hsig(vo[j]);
                float ct = fast_tanh(vc[j]);
                float cn = fg * c0v[j] + ig * ct;
                float hn = og * fast_tanh(cn);
                cnv[j] = cn; hnv[j] = hn;
            }
            *(f32x4*)(out + off)                = hnv;   // h
            *(f32x4*)(out + HN_ELEMS + off)     = cnv;   // c
            *(f32x4*)(out + 2 * HN_ELEMS + off) = hnv;   // h (duplicate)
        }
    }
}

extern "C" void kernel_launch(void* const* d_in, const int* in_sizes, int n_in,
                              void* d_out, int out_size, void* d_ws, size_t ws_size,
                              hipStream_t stream) {
    const float* x  = (const float*)d_in[0];
    const float* c0 = (const float*)d_in[1];
    const float* h0 = (const float*)d_in[2];
    const float* Wf = (const float*)d_in[3];
    const float* Wi = (const float*)d_in[4];
    const float* Wo = (const float*)d_in[5];
    const float* Wc = (const float*)d_in[6];
    const float* Uf = (const float*)d_in[7];
    const float* Ui = (const float*)d_in[8];
    const float* Uo = (const float*)d_in[9];
    const float* Uc = (const float*)d_in[10];
    const float* bf = (const float*)d_in[11];
    const float* bi = (const float*)d_in[12];
    const float* bo = (const float*)d_in[13];
    const float* bc = (const float*)d_in[14];

    u16* Bt   = (u16*)d_ws;                          // 4096 x 2048 bf16 = 16 MB
    u16* Abuf = (u16*)d_ws + (size_t)4 * NH * KTOT;  // 4096 x 2048 bf16 = 16 MB

    static bool attr_done = false;
    if (!attr_done) {
        (void)hipFuncSetAttribute((const void*)lstm_gemm_kernel,
                                  hipFuncAttributeMaxDynamicSharedMemorySize,
                                  131072);
        attr_done = true;
    }

    prep_kernel<<<WT_BLOCKS + (BATCH * KTOT / 8) / 256, 256, 0, stream>>>(
        x, h0, Wf, Wi, Wo, Wc, Uf, Ui, Uo, Uc, Bt, Abuf);

    dim3 gg(BATCH / BM, NH / BNG);   // 16 x 16 = 256 blocks, 1/CU, 8 waves/CU
    lstm_gemm_kernel<<<gg, 512, 131072, stream>>>(Abuf, c0, Bt, bf, bi, bo, bc,
                                                  (float*)d_out);
}